// Round 15
// baseline (306.113 us; speedup 1.0000x reference)
//
#include <hip/hip_runtime.h>
#include <hip/hip_bf16.h>
#include <math.h>

#define NN 50000
#define NE 800000
#define NB ((NN + 255) / 256)
#define NEG 0.2f
#define NHB ((NE + 255) / 256)

typedef __hip_bfloat16 bf16;
typedef __attribute__((ext_vector_type(8))) short s8v;
typedef __attribute__((ext_vector_type(4))) float f4v;
typedef __attribute__((ext_vector_type(2))) float f2v;

__device__ __forceinline__ float bf2f(unsigned short u) {
  union { unsigned int i; float f; } c;
  c.i = ((unsigned int)u) << 16;
  return c.f;
}
__device__ __forceinline__ float blo(unsigned int u) {
  union { unsigned int i; float f; } c;
  c.i = u << 16;
  return c.f;
}
__device__ __forceinline__ float bhi(unsigned int u) {
  union { unsigned int i; float f; } c;
  c.i = u & 0xffff0000u;
  return c.f;
}
__device__ __forceinline__ f2v b2f2(unsigned int u) {
  f2v r;
  r.x = blo(u);
  r.y = bhi(u);
  return r;
}
__device__ __forceinline__ unsigned short f2b(float f) {
  bf16 b = __float2bfloat16(f);
  return __builtin_bit_cast(unsigned short, b);
}
__device__ __forceinline__ float lrelu(float t) { return (t > 0.f) ? t : NEG * t; }

// ---------------- prep: histogram + all fp32->bf16 conversions -------------
#define NX4 (NN * 32)           // x as float4 units
#define NW1 (256 * 128)
#define NW2 (64 * 256)
#define NPQ (128 * 64)
__global__ void prep_k(const int* __restrict__ ei, int* __restrict__ counts,
                       const float* __restrict__ x, const float* __restrict__ W1,
                       const float* __restrict__ W2, const float* __restrict__ mw1,
                       unsigned short* __restrict__ xb, unsigned short* __restrict__ w1t,
                       unsigned short* __restrict__ w2t, unsigned short* __restrict__ pqt) {
  int b = blockIdx.x;
  if (b < NHB) {
    int e = b * 256 + threadIdx.x;
    if (e < NE) atomicAdd(&counts[ei[NE + e]], 1);
    return;
  }
  int i = (b - NHB) * 256 + threadIdx.x;
  if (i < NX4) {
    float4 v = *(const float4*)(x + (size_t)i * 4);
    ushort4 o = {f2b(v.x), f2b(v.y), f2b(v.z), f2b(v.w)};
    *(ushort4*)(xb + (size_t)i * 4) = o;
    return;
  }
  i -= NX4;
  if (i < NW1) {  // w1t[n*128+k] = W1[k*256+n]
    int n = i >> 7, k = i & 127;
    w1t[i] = f2b(W1[(size_t)k * 256 + n]);
    return;
  }
  i -= NW1;
  if (i < NW2) {  // w2t[n*256+k] = W2[k*64+n]
    int n = i >> 8, k = i & 255;
    w2t[i] = f2b(W2[(size_t)k * 64 + n]);
    return;
  }
  i -= NW2;
  if (i < NPQ) {
    int n = i >> 6, k = i & 63;
    float v = (n < 64) ? mw1[(size_t)k * 64 + n] : mw1[(size_t)(64 + k) * 64 + (n - 64)];
    pqt[i] = f2b(v);
  }
}

// ---- folded attention weights: watt[sel*4+h][k] = sum_c W1[k][h*64+c]*att[h][c]
__global__ void attw_k(const float* __restrict__ W1, const float* __restrict__ as1w,
                       const float* __restrict__ ad1w, float* __restrict__ watt) {
  int b = blockIdx.x;   // 8 blocks
  int h = b & 3, sel = b >> 2;
  const float* att = (sel ? ad1w : as1w) + h * 64;
  int k = threadIdx.x;  // 128 threads
  float s = 0.f;
#pragma unroll 8
  for (int c = 0; c < 64; ++c) s += W1[(size_t)k * 256 + h * 64 + c] * att[c];
  watt[(sel * 4 + h) * 128 + k] = s;
}

// ---- per-node layer-1 attention dots (LDS-staged, no shuffles) -----------
__global__ __launch_bounds__(256) void attdot1_k(
    const float* __restrict__ x, const float* __restrict__ watt,
    float* __restrict__ as_, float* __restrict__ ad_) {
  __shared__ float xs[32][132];
  __shared__ float ws[8][132];
  int t = threadIdx.x;
  int n0 = blockIdx.x * 32;
  for (int i = t; i < 1024; i += 256) ws[i >> 7][i & 127] = watt[i];
  for (int i = t; i < 1024; i += 256) {
    int r = i >> 5, c4 = i & 31;
    float4 v = {0.f, 0.f, 0.f, 0.f};
    if (n0 + r < NN) v = *(const float4*)(x + (size_t)(n0 + r) * 128 + c4 * 4);
    *(float4*)&xs[r][c4 * 4] = v;
  }
  __syncthreads();
  int nloc = t >> 3, j = t & 7;
  float s = 0.f;
#pragma unroll
  for (int k = 0; k < 128; k += 4) {
    float4 xv = *(const float4*)&xs[nloc][k];
    float4 wv = *(const float4*)&ws[j][k];
    s += xv.x * wv.x + xv.y * wv.y + xv.z * wv.z + xv.w * wv.w;
  }
  int n = n0 + nloc;
  if (n < NN) {
    if (j < 4) as_[(size_t)n * 4 + j] = s;
    else ad_[(size_t)n * 4 + (j - 4)] = s;
  }
}

// ---------------- scan ----------------
__global__ __launch_bounds__(256) void scan_bsum_k(const int* __restrict__ counts,
                                                   int* __restrict__ bsums) {
  __shared__ int wsum[4];
  int i = blockIdx.x * 256 + threadIdx.x;
  int v = (i < NN) ? counts[i] : 0;
#pragma unroll
  for (int off = 32; off; off >>= 1) v += __shfl_xor(v, off);
  if ((threadIdx.x & 63) == 0) wsum[threadIdx.x >> 6] = v;
  __syncthreads();
  if (threadIdx.x == 0) bsums[blockIdx.x] = wsum[0] + wsum[1] + wsum[2] + wsum[3];
}

__global__ __launch_bounds__(256) void scan_final_k(const int* __restrict__ counts,
                                                    const int* __restrict__ bsums,
                                                    int* __restrict__ offsets,
                                                    int* __restrict__ cursor) {
  __shared__ int s[256];
  __shared__ int wsum[4];
  __shared__ int bpref;
  int t = threadIdx.x;
  int bv = (t < NB && t < (int)blockIdx.x) ? bsums[t] : 0;
#pragma unroll
  for (int off = 32; off; off >>= 1) bv += __shfl_xor(bv, off);
  if ((t & 63) == 0) wsum[t >> 6] = bv;
  __syncthreads();
  if (t == 0) bpref = wsum[0] + wsum[1] + wsum[2] + wsum[3];
  int i = blockIdx.x * 256 + t;
  int v = (i < NN) ? counts[i] : 0;
  s[t] = v;
  __syncthreads();
  for (int off = 1; off < 256; off <<= 1) {
    int u = (t >= off) ? s[t - off] : 0;
    __syncthreads();
    s[t] += u;
    __syncthreads();
  }
  int excl = s[t] - v + bpref;
  if (i < NN) {
    offsets[i] = excl;
    cursor[i] = excl;
    if (i == NN - 1) offsets[NN] = excl + v;
  }
}

__global__ void scatter_k(const int* __restrict__ ei, int* __restrict__ cursor,
                          int2* __restrict__ csr) {
  int e = blockIdx.x * 256 + threadIdx.x;
  if (e >= NE) return;
  int s = ei[e], d = ei[NE + e];
  int pos = atomicAdd(&cursor[d], 1);
  csr[pos] = make_int2(s, e);
}

// ---------------- bf16 MFMA GEMM: C[M,N] = A[M,K] @ Bt[N,K]^T ----------------
template <int DOTS>
__global__ __launch_bounds__(256) void mgemm_k(
    const unsigned short* __restrict__ A, int lda,
    const unsigned short* __restrict__ Bt, int ldb,
    unsigned short* __restrict__ C, int ldc,
    int M, int N, int K,
    const float* __restrict__ ws, const float* __restrict__ wd,
    float* __restrict__ as_, float* __restrict__ ad_, int H) {
  __shared__ unsigned short Asl[64][40];
  __shared__ unsigned short Btl[64][40];
  __shared__ float sdot[64], ddot[64];
  int bm = blockIdx.y * 64, bn = blockIdx.x * 64;
  int t = threadIdx.x;
  int wv = t >> 6, lane = t & 63;
  int wm = (wv >> 1) * 32, wn = (wv & 1) * 32;
  int l16 = lane & 15, lq = lane >> 4;
  if (DOTS && t < 64) { sdot[t] = 0.f; ddot[t] = 0.f; }
  f4v acc[2][2];
#pragma unroll
  for (int mi = 0; mi < 2; ++mi)
#pragma unroll
    for (int ni = 0; ni < 2; ++ni) {
      acc[mi][ni][0] = 0.f; acc[mi][ni][1] = 0.f;
      acc[mi][ni][2] = 0.f; acc[mi][ni][3] = 0.f;
    }
  int sr = t >> 2, sc = (t & 3) * 8;
  for (int k0 = 0; k0 < K; k0 += 32) {
    uint4 av = {0, 0, 0, 0};
    int gr = bm + sr;
    if (gr < M) av = *(const uint4*)(A + (size_t)gr * lda + k0 + sc);
    *(uint4*)&Asl[sr][sc] = av;
    uint4 bv = *(const uint4*)(Bt + (size_t)(bn + sr) * ldb + k0 + sc);
    *(uint4*)&Btl[sr][sc] = bv;
    __syncthreads();
    s8v af[2], bfv[2];
#pragma unroll
    for (int mi = 0; mi < 2; ++mi)
      af[mi] = *(const s8v*)&Asl[wm + mi * 16 + l16][lq * 8];
#pragma unroll
    for (int ni = 0; ni < 2; ++ni)
      bfv[ni] = *(const s8v*)&Btl[wn + ni * 16 + l16][lq * 8];
#pragma unroll
    for (int mi = 0; mi < 2; ++mi)
#pragma unroll
      for (int ni = 0; ni < 2; ++ni)
        acc[mi][ni] = __builtin_amdgcn_mfma_f32_16x16x32_bf16(
            af[mi], bfv[ni], acc[mi][ni], 0, 0, 0);
    __syncthreads();
  }
#pragma unroll
  for (int mi = 0; mi < 2; ++mi)
#pragma unroll
    for (int rr = 0; rr < 4; ++rr) {
      int row = bm + wm + mi * 16 + lq * 4 + rr;
      if (row < M) {
#pragma unroll
        for (int ni = 0; ni < 2; ++ni) {
          int col = bn + wn + ni * 16 + l16;
          C[(size_t)row * ldc + col] = f2b(acc[mi][ni][rr]);
        }
      }
    }
  if (DOTS) {
    int head = blockIdx.x;
    float ps[2][4], pd[2][4];
#pragma unroll
    for (int mi = 0; mi < 2; ++mi)
#pragma unroll
      for (int rr = 0; rr < 4; ++rr) {
        float s = 0.f, d = 0.f;
#pragma unroll
        for (int ni = 0; ni < 2; ++ni) {
          int col = wn + ni * 16 + l16;
          s += acc[mi][ni][rr] * ws[head * 64 + col];
          d += acc[mi][ni][rr] * wd[head * 64 + col];
        }
        ps[mi][rr] = s;
        pd[mi][rr] = d;
      }
#pragma unroll
    for (int off = 1; off < 16; off <<= 1)
#pragma unroll
      for (int mi = 0; mi < 2; ++mi)
#pragma unroll
        for (int rr = 0; rr < 4; ++rr) {
          ps[mi][rr] += __shfl_xor(ps[mi][rr], off);
          pd[mi][rr] += __shfl_xor(pd[mi][rr], off);
        }
    if (l16 == 0) {
#pragma unroll
      for (int mi = 0; mi < 2; ++mi)
#pragma unroll
        for (int rr = 0; rr < 4; ++rr) {
          int rl = wm + mi * 16 + lq * 4 + rr;
          atomicAdd(&sdot[rl], ps[mi][rr]);
          atomicAdd(&ddot[rl], pd[mi][rr]);
        }
    }
    __syncthreads();
    if (t < 64 && bm + t < M) {
      as_[(size_t)(bm + t) * H + head] = sdot[t];
      ad_[(size_t)(bm + t) * H + head] = ddot[t];
    }
  }
}

// ---- per-head post-GEMM: x2 = elu(aggx[:,head,:] @ W1[:,head-block] + b1) ----
__global__ __launch_bounds__(256) void mgemm_hx2_k(
    const unsigned short* __restrict__ A,     // aggx [NN][512]
    const unsigned short* __restrict__ w1t,   // [256][128]
    const float* __restrict__ bias,           // b1 [256]
    unsigned short* __restrict__ C) {         // x2b [NN][256]
  __shared__ unsigned short Asl[64][40];
  __shared__ unsigned short Btl[64][40];
  int head = blockIdx.x;
  int bm = blockIdx.y * 64;
  int t = threadIdx.x;
  int wv = t >> 6, lane = t & 63;
  int wm = (wv >> 1) * 32, wn = (wv & 1) * 32;
  int l16 = lane & 15, lq = lane >> 4;
  f4v acc[2][2];
#pragma unroll
  for (int mi = 0; mi < 2; ++mi)
#pragma unroll
    for (int ni = 0; ni < 2; ++ni) {
      acc[mi][ni][0] = 0.f; acc[mi][ni][1] = 0.f;
      acc[mi][ni][2] = 0.f; acc[mi][ni][3] = 0.f;
    }
  int sr = t >> 2, sc = (t & 3) * 8;
  for (int k0 = 0; k0 < 128; k0 += 32) {
    uint4 av = {0, 0, 0, 0};
    int gr = bm + sr;
    if (gr < NN) av = *(const uint4*)(A + (size_t)gr * 512 + head * 128 + k0 + sc);
    *(uint4*)&Asl[sr][sc] = av;
    uint4 bv = *(const uint4*)(w1t + (size_t)(head * 64 + sr) * 128 + k0 + sc);
    *(uint4*)&Btl[sr][sc] = bv;
    __syncthreads();
    s8v af[2], bfv[2];
#pragma unroll
    for (int mi = 0; mi < 2; ++mi)
      af[mi] = *(const s8v*)&Asl[wm + mi * 16 + l16][lq * 8];
#pragma unroll
    for (int ni = 0; ni < 2; ++ni)
      bfv[ni] = *(const s8v*)&Btl[wn + ni * 16 + l16][lq * 8];
#pragma unroll
    for (int mi = 0; mi < 2; ++mi)
#pragma unroll
      for (int ni = 0; ni < 2; ++ni)
        acc[mi][ni] = __builtin_amdgcn_mfma_f32_16x16x32_bf16(
            af[mi], bfv[ni], acc[mi][ni], 0, 0, 0);
    __syncthreads();
  }
#pragma unroll
  for (int mi = 0; mi < 2; ++mi)
#pragma unroll
    for (int rr = 0; rr < 4; ++rr) {
      int row = bm + wm + mi * 16 + lq * 4 + rr;
      if (row < NN) {
#pragma unroll
        for (int ni = 0; ni < 2; ++ni) {
          int col = head * 64 + wn + ni * 16 + l16;
          float v = acc[mi][ni][rr] + bias[col];
          v = (v > 0.f) ? v : (__expf(v) - 1.f);
          C[(size_t)row * 256 + col] = f2b(v);
        }
      }
    }
}

// ---------------- layer-1 aggregation in INPUT space: 1 wave per node -----
// 4 slots x 16 lanes x uint4 (8 ch): 16 edges/iter, 16B loads, 4 in flight.
__global__ __launch_bounds__(256) void gat_aggx_k(
    const int* __restrict__ offsets, const int2* __restrict__ csr,
    const unsigned short* __restrict__ xb, const float* __restrict__ as_,
    const float* __restrict__ ad_, unsigned short* __restrict__ aggx) {
  __shared__ float exs[4][64][4];
  __shared__ int srcs[4][64];
  int wvx = threadIdx.x >> 6, lane = threadIdx.x & 63;
  int n = blockIdx.x * 4 + wvx;
  int slot = lane >> 4, cp = lane & 15;
  int beg = offsets[n], end = offsets[n + 1];
  float4 adn = *(const float4*)(ad_ + (size_t)n * 4);
  float4 asn = *(const float4*)(as_ + (size_t)n * 4);
  float es0 = __expf(lrelu(asn.x + adn.x));
  float es1 = __expf(lrelu(asn.y + adn.y));
  float es2 = __expf(lrelu(asn.z + adn.z));
  float es3 = __expf(lrelu(asn.w + adn.w));
  float d0 = es0, d1 = es1, d2 = es2, d3 = es3;
  f2v a[4][4];   // [head][ch-pair 01,23,45,67]
#pragma unroll
  for (int h = 0; h < 4; ++h)
#pragma unroll
    for (int c = 0; c < 4; ++c) a[h][c] = 0.f;
  if (slot == 0) {
    uint4 sv = *(const uint4*)(xb + (size_t)n * 128 + cp * 8);
    f2v x0 = b2f2(sv.x), x1 = b2f2(sv.y), x2 = b2f2(sv.z), x3 = b2f2(sv.w);
    a[0][0] = es0 * x0; a[0][1] = es0 * x1; a[0][2] = es0 * x2; a[0][3] = es0 * x3;
    a[1][0] = es1 * x0; a[1][1] = es1 * x1; a[1][2] = es1 * x2; a[1][3] = es1 * x3;
    a[2][0] = es2 * x0; a[2][1] = es2 * x1; a[2][2] = es2 * x2; a[2][3] = es2 * x3;
    a[3][0] = es3 * x0; a[3][1] = es3 * x1; a[3][2] = es3 * x2; a[3][3] = es3 * x3;
  }
  for (int base = beg; base < end; base += 64) {
    int cnt = min(64, end - base);
    int src = 0;
    float e0 = 0.f, e1 = 0.f, e2 = 0.f, e3 = 0.f;
    if (lane < cnt) {
      src = csr[base + lane].x;
      float4 a4 = *(const float4*)(as_ + (size_t)src * 4);
      e0 = __expf(lrelu(a4.x + adn.x));
      e1 = __expf(lrelu(a4.y + adn.y));
      e2 = __expf(lrelu(a4.z + adn.z));
      e3 = __expf(lrelu(a4.w + adn.w));
    }
    float s0 = e0, s1 = e1, s2 = e2, s3 = e3;
#pragma unroll
    for (int off = 32; off; off >>= 1) {
      s0 += __shfl_xor(s0, off);
      s1 += __shfl_xor(s1, off);
      s2 += __shfl_xor(s2, off);
      s3 += __shfl_xor(s3, off);
    }
    d0 += s0; d1 += s1; d2 += s2; d3 += s3;
    float4 ex4 = {e0, e1, e2, e3};
    *(float4*)(&exs[wvx][lane][0]) = ex4;
    srcs[wvx][lane] = src;
    __builtin_amdgcn_wave_barrier();
    int i = slot;
    for (; i + 12 < cnt; i += 16) {
      uint4 r[4];
      float4 w[4];
#pragma unroll
      for (int j = 0; j < 4; ++j) {
        int e = i + 4 * j;
        r[j] = *(const uint4*)(xb + (size_t)srcs[wvx][e] * 128 + cp * 8);
        w[j] = *(const float4*)(&exs[wvx][e][0]);
      }
#pragma unroll
      for (int j = 0; j < 4; ++j) {
        f2v x0 = b2f2(r[j].x), x1 = b2f2(r[j].y), x2 = b2f2(r[j].z), x3 = b2f2(r[j].w);
        a[0][0] += w[j].x * x0; a[0][1] += w[j].x * x1;
        a[0][2] += w[j].x * x2; a[0][3] += w[j].x * x3;
        a[1][0] += w[j].y * x0; a[1][1] += w[j].y * x1;
        a[1][2] += w[j].y * x2; a[1][3] += w[j].y * x3;
        a[2][0] += w[j].z * x0; a[2][1] += w[j].z * x1;
        a[2][2] += w[j].z * x2; a[2][3] += w[j].z * x3;
        a[3][0] += w[j].w * x0; a[3][1] += w[j].w * x1;
        a[3][2] += w[j].w * x2; a[3][3] += w[j].w * x3;
      }
    }
    for (; i < cnt; i += 4) {
      uint4 r = *(const uint4*)(xb + (size_t)srcs[wvx][i] * 128 + cp * 8);
      float4 w = *(const float4*)(&exs[wvx][i][0]);
      f2v x0 = b2f2(r.x), x1 = b2f2(r.y), x2 = b2f2(r.z), x3 = b2f2(r.w);
      a[0][0] += w.x * x0; a[0][1] += w.x * x1; a[0][2] += w.x * x2; a[0][3] += w.x * x3;
      a[1][0] += w.y * x0; a[1][1] += w.y * x1; a[1][2] += w.y * x2; a[1][3] += w.y * x3;
      a[2][0] += w.z * x0; a[2][1] += w.z * x1; a[2][2] += w.z * x2; a[2][3] += w.z * x3;
      a[3][0] += w.w * x0; a[3][1] += w.w * x1; a[3][2] += w.w * x2; a[3][3] += w.w * x3;
    }
  }
#pragma unroll
  for (int off = 16; off <= 32; off <<= 1)
#pragma unroll
    for (int h = 0; h < 4; ++h)
#pragma unroll
      for (int c = 0; c < 4; ++c) {
        a[h][c].x += __shfl_xor(a[h][c].x, off);
        a[h][c].y += __shfl_xor(a[h][c].y, off);
      }
  if (slot == 0) {
    float inv[4] = {1.f / d0, 1.f / d1, 1.f / d2, 1.f / d3};
    size_t rb = (size_t)n * 512 + cp * 8;
#pragma unroll
    for (int h = 0; h < 4; ++h) {
      ushort4 olo = {f2b(a[h][0].x * inv[h]), f2b(a[h][0].y * inv[h]),
                     f2b(a[h][1].x * inv[h]), f2b(a[h][1].y * inv[h])};
      ushort4 ohi = {f2b(a[h][2].x * inv[h]), f2b(a[h][2].y * inv[h]),
                     f2b(a[h][3].x * inv[h]), f2b(a[h][3].y * inv[h])};
      *(ushort4*)(aggx + rb + h * 128) = olo;
      *(ushort4*)(aggx + rb + h * 128 + 4) = ohi;
    }
  }
}

// ---------------- GAT layer-2 aggregation: 1 wave per node, H=1 ----------
__global__ __launch_bounds__(256) void gat_agg1_k(
    const int* __restrict__ offsets, const int2* __restrict__ csr,
    const unsigned short* __restrict__ h, const float* __restrict__ as_,
    const float* __restrict__ ad_, const float* __restrict__ bias,
    unsigned short* __restrict__ out) {
  __shared__ float exs[4][64];
  __shared__ int srcs[4][64];
  int wvx = threadIdx.x >> 6, lane = threadIdx.x & 63;
  int n = blockIdx.x * 4 + wvx;
  int slot = lane >> 4, cp = lane & 15;
  int beg = offsets[n], end = offsets[n + 1];
  float adn = ad_[n];
  float eself = __expf(lrelu(as_[n] + adn));
  float den = eself;
  f2v a01 = 0.f, a23 = 0.f;
  if (slot == 0) {
    uint2 sv = *(const uint2*)(h + (size_t)n * 64 + cp * 4);
    a01 = eself * b2f2(sv.x);
    a23 = eself * b2f2(sv.y);
  }
  for (int base = beg; base < end; base += 64) {
    int cnt = min(64, end - base);
    int src = 0;
    float ex = 0.f;
    if (lane < cnt) {
      src = csr[base + lane].x;
      ex = __expf(lrelu(as_[src] + adn));
    }
    float s = ex;
#pragma unroll
    for (int off = 32; off; off >>= 1) s += __shfl_xor(s, off);
    den += s;
    exs[wvx][lane] = ex;
    srcs[wvx][lane] = src;
    __builtin_amdgcn_wave_barrier();
    int i = slot;
    for (; i + 12 < cnt; i += 16) {
      uint2 r[4];
      int i0 = i, i1 = i + 4, i2 = i + 8, i3 = i + 12;
      r[0] = *(const uint2*)(h + (size_t)srcs[wvx][i0] * 64 + cp * 4);
      r[1] = *(const uint2*)(h + (size_t)srcs[wvx][i1] * 64 + cp * 4);
      r[2] = *(const uint2*)(h + (size_t)srcs[wvx][i2] * 64 + cp * 4);
      r[3] = *(const uint2*)(h + (size_t)srcs[wvx][i3] * 64 + cp * 4);
      float w0 = exs[wvx][i0], w1 = exs[wvx][i1], w2 = exs[wvx][i2], w3 = exs[wvx][i3];
      a01 += w0 * b2f2(r[0].x); a23 += w0 * b2f2(r[0].y);
      a01 += w1 * b2f2(r[1].x); a23 += w1 * b2f2(r[1].y);
      a01 += w2 * b2f2(r[2].x); a23 += w2 * b2f2(r[2].y);
      a01 += w3 * b2f2(r[3].x); a23 += w3 * b2f2(r[3].y);
    }
    for (; i < cnt; i += 4) {
      int si = srcs[wvx][i];
      float w = exs[wvx][i];
      uint2 r = *(const uint2*)(h + (size_t)si * 64 + cp * 4);
      a01 += w * b2f2(r.x);
      a23 += w * b2f2(r.y);
    }
  }
#pragma unroll
  for (int off = 16; off <= 32; off <<= 1) {
    a01.x += __shfl_xor(a01.x, off);
    a01.y += __shfl_xor(a01.y, off);
    a23.x += __shfl_xor(a23.x, off);
    a23.y += __shfl_xor(a23.y, off);
  }
  if (slot == 0) {
    float inv = 1.f / den;
    float4 b4 = *(const float4*)(bias + cp * 4);
    ushort4 ov;
    ov.x = f2b(a01.x * inv + b4.x);
    ov.y = f2b(a01.y * inv + b4.y);
    ov.z = f2b(a23.x * inv + b4.z);
    ov.w = f2b(a23.y * inv + b4.w);
    *(ushort4*)(out + (size_t)n * 64 + cp * 4) = ov;
  }
}

// ---------------- dst-grouped edge MLP: 1 wave per dst node ---------------
__global__ __launch_bounds__(256) void edge_out_k(
    const int* __restrict__ offsets, const int2* __restrict__ csr,
    const unsigned short* __restrict__ pq,
    const float* __restrict__ mb1, const float* __restrict__ w2,
    const float* __restrict__ mb2, float* __restrict__ out) {
  int wvx = threadIdx.x >> 6, lane = threadIdx.x & 63;
  int n = blockIdx.x * 4 + wvx;
  int slot = lane >> 4, cp = lane & 15;
  int beg = offsets[n], end = offsets[n + 1];
  uint2 qv = *(const uint2*)(pq + (size_t)n * 128 + 64 + cp * 4);
  f2v base01 = b2f2(qv.x), base23 = b2f2(qv.y);
  {
    float4 mb = *(const float4*)(mb1 + cp * 4);
    base01.x += mb.x; base01.y += mb.y;
    base23.x += mb.z; base23.y += mb.w;
  }
  f2v w01, w23;
  {
    float4 wv4 = *(const float4*)(w2 + cp * 4);
    w01.x = wv4.x; w01.y = wv4.y; w23.x = wv4.z; w23.y = wv4.w;
  }
  float b2v = mb2[0];
  for (int base = beg; base < end; base += 8) {
    int i0 = base + slot, i1 = base + 4 + slot;
    bool ok0 = (i0 < end), ok1 = (i1 < end);
    int2 se0 = {0, 0}, se1 = {0, 0};
    if (ok0) se0 = csr[i0];
    if (ok1) se1 = csr[i1];
    float r0 = 0.f, r1 = 0.f;
    if (ok0) {
      uint2 pv = *(const uint2*)(pq + (size_t)se0.x * 128 + cp * 4);
      f2v v01 = b2f2(pv.x) + base01;
      f2v v23 = b2f2(pv.y) + base23;
      v01.x = fmaxf(v01.x, 0.f); v01.y = fmaxf(v01.y, 0.f);
      v23.x = fmaxf(v23.x, 0.f); v23.y = fmaxf(v23.y, 0.f);
      f2v rv = v01 * w01 + v23 * w23;
      r0 = rv.x + rv.y;
    }
    if (ok1) {
      uint2 pv = *(const uint2*)(pq + (size_t)se1.x * 128 + cp * 4);
      f2v v01 = b2f2(pv.x) + base01;
      f2v v23 = b2f2(pv.y) + base23;
      v01.x = fmaxf(v01.x, 0.f); v01.y = fmaxf(v01.y, 0.f);
      v23.x = fmaxf(v23.x, 0.f); v23.y = fmaxf(v23.y, 0.f);
      f2v rv = v01 * w01 + v23 * w23;
      r1 = rv.x + rv.y;
    }
#pragma unroll
    for (int off = 8; off; off >>= 1) {
      r0 += __shfl_xor(r0, off);
      r1 += __shfl_xor(r1, off);
    }
    if (cp == 0) {
      if (ok0) out[se0.y] = r0 + b2v;
      if (ok1) out[se1.y] = r1 + b2v;
    }
  }
}

extern "C" void kernel_launch(void* const* d_in, const int* in_sizes, int n_in,
                              void* d_out, int out_size, void* d_ws, size_t ws_size,
                              hipStream_t stream) {
  const float* x = (const float*)d_in[0];
  const int* ei = (const int*)d_in[1];
  const float* W1 = (const float*)d_in[2];
  const float* as1w = (const float*)d_in[3];
  const float* ad1w = (const float*)d_in[4];
  const float* b1 = (const float*)d_in[5];
  const float* W2 = (const float*)d_in[6];
  const float* as2w = (const float*)d_in[7];
  const float* ad2w = (const float*)d_in[8];
  const float* b2 = (const float*)d_in[9];
  const float* mw1 = (const float*)d_in[10];
  const float* mb1 = (const float*)d_in[11];
  const float* mw2 = (const float*)d_in[12];
  const float* mb2 = (const float*)d_in[13];
  float* out = (float*)d_out;

  char* ws = (char*)d_ws;
  size_t o = 0;
  auto alloc = [&](size_t bytes) {
    void* ptr = ws + o;
    o += (bytes + 255) & ~(size_t)255;
    return ptr;
  };
  int* counts = (int*)alloc((size_t)NN * 4);
  int* offsets = (int*)alloc((size_t)(NN + 1) * 4);
  int* cursor = (int*)alloc((size_t)NN * 4);
  int* bsums = (int*)alloc((size_t)NB * 4);
  int2* csr = (int2*)alloc((size_t)NE * 8);
  unsigned short* xb = (unsigned short*)alloc((size_t)NN * 128 * 2);
  unsigned short* w1t = (unsigned short*)alloc((size_t)256 * 128 * 2);
  unsigned short* w2t = (unsigned short*)alloc((size_t)64 * 256 * 2);
  unsigned short* pqt = (unsigned short*)alloc((size_t)128 * 64 * 2);
  float* watt = (float*)alloc((size_t)8 * 128 * 4);
  unsigned short* big = (unsigned short*)alloc((size_t)NN * 512 * 2);  // aggx -> h2b/pq
  float* a_s1 = (float*)alloc((size_t)NN * 4 * 4);
  float* a_d1 = (float*)alloc((size_t)NN * 4 * 4);
  unsigned short* x2b = (unsigned short*)alloc((size_t)NN * 256 * 2);
  unsigned short* yb = (unsigned short*)alloc((size_t)NN * 64 * 2);
  unsigned short* aggx = big;                  // NN*512, dead after hx2
  unsigned short* h2b = big;                   // NN*64
  unsigned short* pq = big + (size_t)NN * 64;  // NN*128, [p|q]

  // CSR build + conversions + folded attention weights
  hipMemsetAsync(counts, 0, (size_t)NN * 4, stream);
  attw_k<<<8, 128, 0, stream>>>(W1, as1w, ad1w, watt);
  prep_k<<<NHB + (NX4 + NW1 + NW2 + NPQ + 255) / 256, 256, 0, stream>>>(
      ei, counts, x, W1, W2, mw1, xb, w1t, w2t, pqt);
  attdot1_k<<<(NN + 31) / 32, 256, 0, stream>>>(x, watt, a_s1, a_d1);
  scan_bsum_k<<<NB, 256, 0, stream>>>(counts, bsums);
  scan_final_k<<<NB, 256, 0, stream>>>(counts, bsums, offsets, cursor);
  scatter_k<<<(NE + 255) / 256, 256, 0, stream>>>(ei, cursor, csr);

  int gy = (NN + 63) / 64;
  // Layer 1 (input-space aggregation): aggregate x-rows; post-GEMM per head
  gat_aggx_k<<<NN / 4, 256, 0, stream>>>(offsets, csr, xb, a_s1, a_d1, aggx);
  mgemm_hx2_k<<<dim3(4, gy), 256, 0, stream>>>(aggx, w1t, b1, x2b);

  // Layer 2: h2 = x2 @ W2 (MFMA) + fused dots; aggregate -> y (bf16)
  mgemm_k<1><<<dim3(1, gy), 256, 0, stream>>>(x2b, 256, w2t, 256, h2b, 64,
                                              NN, 64, 256, as2w, ad2w, a_s1, a_d1, 1);
  gat_agg1_k<<<NN / 4, 256, 0, stream>>>(offsets, csr, h2b, a_s1, a_d1, b2, yb);

  // Edge MLP: pq = y @ [mw1[:64] | mw1[64:]]  (one MFMA GEMM, N=128)
  mgemm_k<0><<<dim3(2, gy), 256, 0, stream>>>(yb, 64, pqt, 64, pq, 128,
                                              NN, 128, 64, nullptr, nullptr,
                                              nullptr, nullptr, 0);

  // Final per-edge output (dst-grouped)
  edge_out_k<<<NN / 4, 256, 0, stream>>>(offsets, csr, pq, mb1, mw2, mb2, out);
}

// Round 16
// 273.405 us; speedup vs baseline: 1.1196x; 1.1196x over previous
//
#include <hip/hip_runtime.h>
#include <hip/hip_bf16.h>
#include <math.h>

#define NN 50000
#define NE 800000
#define NB ((NN + 255) / 256)
#define NEG 0.2f
#define NHB ((NE + 255) / 256)

typedef __hip_bfloat16 bf16;
typedef __attribute__((ext_vector_type(8))) short s8v;
typedef __attribute__((ext_vector_type(4))) float f4v;
typedef __attribute__((ext_vector_type(2))) float f2v;

__device__ __forceinline__ float bf2f(unsigned short u) {
  union { unsigned int i; float f; } c;
  c.i = ((unsigned int)u) << 16;
  return c.f;
}
__device__ __forceinline__ float blo(unsigned int u) {
  union { unsigned int i; float f; } c;
  c.i = u << 16;
  return c.f;
}
__device__ __forceinline__ float bhi(unsigned int u) {
  union { unsigned int i; float f; } c;
  c.i = u & 0xffff0000u;
  return c.f;
}
__device__ __forceinline__ f2v b2f2(unsigned int u) {
  f2v r;
  r.x = blo(u);
  r.y = bhi(u);
  return r;
}
__device__ __forceinline__ unsigned short f2b(float f) {
  bf16 b = __float2bfloat16(f);
  return __builtin_bit_cast(unsigned short, b);
}
__device__ __forceinline__ float lrelu(float t) { return (t > 0.f) ? t : NEG * t; }

// ---------------- prep: histogram + conversions + folded att weights -------
#define NX4 (NN * 32)           // x as float4 units
#define NW1 (256 * 128)
#define NW2 (64 * 256)
#define NPQ (128 * 64)
#define NWATT 1024
__global__ void prep_k(const int* __restrict__ ei, int* __restrict__ counts,
                       const float* __restrict__ x, const float* __restrict__ W1,
                       const float* __restrict__ W2, const float* __restrict__ mw1,
                       const float* __restrict__ as1w, const float* __restrict__ ad1w,
                       unsigned short* __restrict__ xb, unsigned short* __restrict__ w1t,
                       unsigned short* __restrict__ w2t, unsigned short* __restrict__ pqt,
                       float* __restrict__ watt) {
  int b = blockIdx.x;
  if (b < NHB) {
    int e = b * 256 + threadIdx.x;
    if (e < NE) atomicAdd(&counts[ei[NE + e]], 1);
    return;
  }
  int i = (b - NHB) * 256 + threadIdx.x;
  if (i < NX4) {
    float4 v = *(const float4*)(x + (size_t)i * 4);
    ushort4 o = {f2b(v.x), f2b(v.y), f2b(v.z), f2b(v.w)};
    *(ushort4*)(xb + (size_t)i * 4) = o;
    return;
  }
  i -= NX4;
  if (i < NW1) {  // w1t[n*128+k] = W1[k*256+n]
    int n = i >> 7, k = i & 127;
    w1t[i] = f2b(W1[(size_t)k * 256 + n]);
    return;
  }
  i -= NW1;
  if (i < NW2) {  // w2t[n*256+k] = W2[k*64+n]
    int n = i >> 8, k = i & 255;
    w2t[i] = f2b(W2[(size_t)k * 64 + n]);
    return;
  }
  i -= NW2;
  if (i < NPQ) {
    int n = i >> 6, k = i & 63;
    float v = (n < 64) ? mw1[(size_t)k * 64 + n] : mw1[(size_t)(64 + k) * 64 + (n - 64)];
    pqt[i] = f2b(v);
    return;
  }
  i -= NPQ;
  if (i < NWATT) {  // watt[sel*4+h][k] = sum_c W1[k][h*64+c]*att[h][c]
    int sel = i >> 9, h = (i >> 7) & 3, k = i & 127;
    const float* att = (sel ? ad1w : as1w) + h * 64;
    float s = 0.f;
#pragma unroll 8
    for (int c = 0; c < 64; ++c) s += W1[(size_t)k * 256 + h * 64 + c] * att[c];
    watt[i] = s;
  }
}

// ---- per-node layer-1 attention dots (LDS-staged, no shuffles) -----------
__global__ __launch_bounds__(256) void attdot1_k(
    const float* __restrict__ x, const float* __restrict__ watt,
    float* __restrict__ as_, float* __restrict__ ad_) {
  __shared__ float xs[32][132];
  __shared__ float ws[8][132];
  int t = threadIdx.x;
  int n0 = blockIdx.x * 32;
  for (int i = t; i < 1024; i += 256) ws[i >> 7][i & 127] = watt[i];
  for (int i = t; i < 1024; i += 256) {
    int r = i >> 5, c4 = i & 31;
    float4 v = {0.f, 0.f, 0.f, 0.f};
    if (n0 + r < NN) v = *(const float4*)(x + (size_t)(n0 + r) * 128 + c4 * 4);
    *(float4*)&xs[r][c4 * 4] = v;
  }
  __syncthreads();
  int nloc = t >> 3, j = t & 7;
  float s = 0.f;
#pragma unroll
  for (int k = 0; k < 128; k += 4) {
    float4 xv = *(const float4*)&xs[nloc][k];
    float4 wv = *(const float4*)&ws[j][k];
    s += xv.x * wv.x + xv.y * wv.y + xv.z * wv.z + xv.w * wv.w;
  }
  int n = n0 + nloc;
  if (n < NN) {
    if (j < 4) as_[(size_t)n * 4 + j] = s;
    else ad_[(size_t)n * 4 + (j - 4)] = s;
  }
}

// ---------------- scan ----------------
__global__ __launch_bounds__(256) void scan_bsum_k(const int* __restrict__ counts,
                                                   int* __restrict__ bsums) {
  __shared__ int wsum[4];
  int i = blockIdx.x * 256 + threadIdx.x;
  int v = (i < NN) ? counts[i] : 0;
#pragma unroll
  for (int off = 32; off; off >>= 1) v += __shfl_xor(v, off);
  if ((threadIdx.x & 63) == 0) wsum[threadIdx.x >> 6] = v;
  __syncthreads();
  if (threadIdx.x == 0) bsums[blockIdx.x] = wsum[0] + wsum[1] + wsum[2] + wsum[3];
}

__global__ __launch_bounds__(256) void scan_final_k(const int* __restrict__ counts,
                                                    const int* __restrict__ bsums,
                                                    int* __restrict__ offsets,
                                                    int* __restrict__ cursor) {
  __shared__ int s[256];
  __shared__ int wsum[4];
  __shared__ int bpref;
  int t = threadIdx.x;
  int bv = (t < NB && t < (int)blockIdx.x) ? bsums[t] : 0;
#pragma unroll
  for (int off = 32; off; off >>= 1) bv += __shfl_xor(bv, off);
  if ((t & 63) == 0) wsum[t >> 6] = bv;
  __syncthreads();
  if (t == 0) bpref = wsum[0] + wsum[1] + wsum[2] + wsum[3];
  int i = blockIdx.x * 256 + t;
  int v = (i < NN) ? counts[i] : 0;
  s[t] = v;
  __syncthreads();
  for (int off = 1; off < 256; off <<= 1) {
    int u = (t >= off) ? s[t - off] : 0;
    __syncthreads();
    s[t] += u;
    __syncthreads();
  }
  int excl = s[t] - v + bpref;
  if (i < NN) {
    offsets[i] = excl;
    cursor[i] = excl;
    if (i == NN - 1) offsets[NN] = excl + v;
  }
}

__global__ void scatter_k(const int* __restrict__ ei, int* __restrict__ cursor,
                          int2* __restrict__ csr) {
  int e = blockIdx.x * 256 + threadIdx.x;
  if (e >= NE) return;
  int s = ei[e], d = ei[NE + e];
  int pos = atomicAdd(&cursor[d], 1);
  csr[pos] = make_int2(s, e);
}

// ---------------- bf16 MFMA GEMM: C[M,N] = A[M,K] @ Bt[N,K]^T ----------------
template <int DOTS>
__global__ __launch_bounds__(256) void mgemm_k(
    const unsigned short* __restrict__ A, int lda,
    const unsigned short* __restrict__ Bt, int ldb,
    unsigned short* __restrict__ C, int ldc,
    int M, int N, int K,
    const float* __restrict__ ws, const float* __restrict__ wd,
    float* __restrict__ as_, float* __restrict__ ad_, int H) {
  __shared__ unsigned short Asl[64][40];
  __shared__ unsigned short Btl[64][40];
  __shared__ float sdot[64], ddot[64];
  int bm = blockIdx.y * 64, bn = blockIdx.x * 64;
  int t = threadIdx.x;
  int wv = t >> 6, lane = t & 63;
  int wm = (wv >> 1) * 32, wn = (wv & 1) * 32;
  int l16 = lane & 15, lq = lane >> 4;
  if (DOTS && t < 64) { sdot[t] = 0.f; ddot[t] = 0.f; }
  f4v acc[2][2];
#pragma unroll
  for (int mi = 0; mi < 2; ++mi)
#pragma unroll
    for (int ni = 0; ni < 2; ++ni) {
      acc[mi][ni][0] = 0.f; acc[mi][ni][1] = 0.f;
      acc[mi][ni][2] = 0.f; acc[mi][ni][3] = 0.f;
    }
  int sr = t >> 2, sc = (t & 3) * 8;
  for (int k0 = 0; k0 < K; k0 += 32) {
    uint4 av = {0, 0, 0, 0};
    int gr = bm + sr;
    if (gr < M) av = *(const uint4*)(A + (size_t)gr * lda + k0 + sc);
    *(uint4*)&Asl[sr][sc] = av;
    uint4 bv = *(const uint4*)(Bt + (size_t)(bn + sr) * ldb + k0 + sc);
    *(uint4*)&Btl[sr][sc] = bv;
    __syncthreads();
    s8v af[2], bfv[2];
#pragma unroll
    for (int mi = 0; mi < 2; ++mi)
      af[mi] = *(const s8v*)&Asl[wm + mi * 16 + l16][lq * 8];
#pragma unroll
    for (int ni = 0; ni < 2; ++ni)
      bfv[ni] = *(const s8v*)&Btl[wn + ni * 16 + l16][lq * 8];
#pragma unroll
    for (int mi = 0; mi < 2; ++mi)
#pragma unroll
      for (int ni = 0; ni < 2; ++ni)
        acc[mi][ni] = __builtin_amdgcn_mfma_f32_16x16x32_bf16(
            af[mi], bfv[ni], acc[mi][ni], 0, 0, 0);
    __syncthreads();
  }
#pragma unroll
  for (int mi = 0; mi < 2; ++mi)
#pragma unroll
    for (int rr = 0; rr < 4; ++rr) {
      int row = bm + wm + mi * 16 + lq * 4 + rr;
      if (row < M) {
#pragma unroll
        for (int ni = 0; ni < 2; ++ni) {
          int col = bn + wn + ni * 16 + l16;
          C[(size_t)row * ldc + col] = f2b(acc[mi][ni][rr]);
        }
      }
    }
  if (DOTS) {
    int head = blockIdx.x;
    float ps[2][4], pd[2][4];
#pragma unroll
    for (int mi = 0; mi < 2; ++mi)
#pragma unroll
      for (int rr = 0; rr < 4; ++rr) {
        float s = 0.f, d = 0.f;
#pragma unroll
        for (int ni = 0; ni < 2; ++ni) {
          int col = wn + ni * 16 + l16;
          s += acc[mi][ni][rr] * ws[head * 64 + col];
          d += acc[mi][ni][rr] * wd[head * 64 + col];
        }
        ps[mi][rr] = s;
        pd[mi][rr] = d;
      }
#pragma unroll
    for (int off = 1; off < 16; off <<= 1)
#pragma unroll
      for (int mi = 0; mi < 2; ++mi)
#pragma unroll
        for (int rr = 0; rr < 4; ++rr) {
          ps[mi][rr] += __shfl_xor(ps[mi][rr], off);
          pd[mi][rr] += __shfl_xor(pd[mi][rr], off);
        }
    if (l16 == 0) {
#pragma unroll
      for (int mi = 0; mi < 2; ++mi)
#pragma unroll
        for (int rr = 0; rr < 4; ++rr) {
          int rl = wm + mi * 16 + lq * 4 + rr;
          atomicAdd(&sdot[rl], ps[mi][rr]);
          atomicAdd(&ddot[rl], pd[mi][rr]);
        }
    }
    __syncthreads();
    if (t < 64 && bm + t < M) {
      as_[(size_t)(bm + t) * H + head] = sdot[t];
      ad_[(size_t)(bm + t) * H + head] = ddot[t];
    }
  }
}

// ---- per-head post-GEMM: x2 = elu(aggx[:,head,:] @ W1[:,head-block] + b1) ----
__global__ __launch_bounds__(256) void mgemm_hx2_k(
    const unsigned short* __restrict__ A,     // aggx [NN][512]
    const unsigned short* __restrict__ w1t,   // [256][128]
    const float* __restrict__ bias,           // b1 [256]
    unsigned short* __restrict__ C) {         // x2b [NN][256]
  __shared__ unsigned short Asl[64][40];
  __shared__ unsigned short Btl[64][40];
  int head = blockIdx.x;
  int bm = blockIdx.y * 64;
  int t = threadIdx.x;
  int wv = t >> 6, lane = t & 63;
  int wm = (wv >> 1) * 32, wn = (wv & 1) * 32;
  int l16 = lane & 15, lq = lane >> 4;
  f4v acc[2][2];
#pragma unroll
  for (int mi = 0; mi < 2; ++mi)
#pragma unroll
    for (int ni = 0; ni < 2; ++ni) {
      acc[mi][ni][0] = 0.f; acc[mi][ni][1] = 0.f;
      acc[mi][ni][2] = 0.f; acc[mi][ni][3] = 0.f;
    }
  int sr = t >> 2, sc = (t & 3) * 8;
  for (int k0 = 0; k0 < 128; k0 += 32) {
    uint4 av = {0, 0, 0, 0};
    int gr = bm + sr;
    if (gr < NN) av = *(const uint4*)(A + (size_t)gr * 512 + head * 128 + k0 + sc);
    *(uint4*)&Asl[sr][sc] = av;
    uint4 bv = *(const uint4*)(w1t + (size_t)(head * 64 + sr) * 128 + k0 + sc);
    *(uint4*)&Btl[sr][sc] = bv;
    __syncthreads();
    s8v af[2], bfv[2];
#pragma unroll
    for (int mi = 0; mi < 2; ++mi)
      af[mi] = *(const s8v*)&Asl[wm + mi * 16 + l16][lq * 8];
#pragma unroll
    for (int ni = 0; ni < 2; ++ni)
      bfv[ni] = *(const s8v*)&Btl[wn + ni * 16 + l16][lq * 8];
#pragma unroll
    for (int mi = 0; mi < 2; ++mi)
#pragma unroll
      for (int ni = 0; ni < 2; ++ni)
        acc[mi][ni] = __builtin_amdgcn_mfma_f32_16x16x32_bf16(
            af[mi], bfv[ni], acc[mi][ni], 0, 0, 0);
    __syncthreads();
  }
#pragma unroll
  for (int mi = 0; mi < 2; ++mi)
#pragma unroll
    for (int rr = 0; rr < 4; ++rr) {
      int row = bm + wm + mi * 16 + lq * 4 + rr;
      if (row < NN) {
#pragma unroll
        for (int ni = 0; ni < 2; ++ni) {
          int col = head * 64 + wn + ni * 16 + l16;
          float v = acc[mi][ni][rr] + bias[col];
          v = (v > 0.f) ? v : (__expf(v) - 1.f);
          C[(size_t)row * 256 + col] = f2b(v);
        }
      }
    }
}

// ---------------- layer-1 aggregation in INPUT space: 1 wave per node -----
// Round-14 best config: 2 slots x 32 lanes x uint2, 4-deep window, f2v accs.
__global__ __launch_bounds__(256) void gat_aggx_k(
    const int* __restrict__ offsets, const int2* __restrict__ csr,
    const unsigned short* __restrict__ xb, const float* __restrict__ as_,
    const float* __restrict__ ad_, unsigned short* __restrict__ aggx) {
  __shared__ float exs[4][64][4];
  __shared__ int srcs[4][64];
  int wvx = threadIdx.x >> 6, lane = threadIdx.x & 63;
  int n = blockIdx.x * 4 + wvx;
  int slot = lane >> 5, cp = lane & 31;
  int beg = offsets[n], end = offsets[n + 1];
  float4 adn = *(const float4*)(ad_ + (size_t)n * 4);
  float4 asn = *(const float4*)(as_ + (size_t)n * 4);
  float es0 = __expf(lrelu(asn.x + adn.x));
  float es1 = __expf(lrelu(asn.y + adn.y));
  float es2 = __expf(lrelu(asn.z + adn.z));
  float es3 = __expf(lrelu(asn.w + adn.w));
  float d0 = es0, d1 = es1, d2 = es2, d3 = es3;
  f2v a01[4], a23[4];
#pragma unroll
  for (int h = 0; h < 4; ++h) { a01[h] = 0.f; a23[h] = 0.f; }
  if (slot == 0) {
    uint2 sv = *(const uint2*)(xb + (size_t)n * 128 + cp * 4);
    f2v x01 = b2f2(sv.x), x23 = b2f2(sv.y);
    a01[0] = es0 * x01; a23[0] = es0 * x23;
    a01[1] = es1 * x01; a23[1] = es1 * x23;
    a01[2] = es2 * x01; a23[2] = es2 * x23;
    a01[3] = es3 * x01; a23[3] = es3 * x23;
  }
  for (int base = beg; base < end; base += 64) {
    int cnt = min(64, end - base);
    int src = 0;
    float e0 = 0.f, e1 = 0.f, e2 = 0.f, e3 = 0.f;
    if (lane < cnt) {
      src = csr[base + lane].x;
      float4 a4 = *(const float4*)(as_ + (size_t)src * 4);
      e0 = __expf(lrelu(a4.x + adn.x));
      e1 = __expf(lrelu(a4.y + adn.y));
      e2 = __expf(lrelu(a4.z + adn.z));
      e3 = __expf(lrelu(a4.w + adn.w));
    }
    float s0 = e0, s1 = e1, s2 = e2, s3 = e3;
#pragma unroll
    for (int off = 32; off; off >>= 1) {
      s0 += __shfl_xor(s0, off);
      s1 += __shfl_xor(s1, off);
      s2 += __shfl_xor(s2, off);
      s3 += __shfl_xor(s3, off);
    }
    d0 += s0; d1 += s1; d2 += s2; d3 += s3;
    float4 ex4 = {e0, e1, e2, e3};
    *(float4*)(&exs[wvx][lane][0]) = ex4;
    srcs[wvx][lane] = src;
    __builtin_amdgcn_wave_barrier();
    int i = slot;
    for (; i + 6 < cnt; i += 8) {
      uint2 r[4];
      float4 w[4];
#pragma unroll
      for (int j = 0; j < 4; ++j) {
        int e = i + 2 * j;
        r[j] = *(const uint2*)(xb + (size_t)srcs[wvx][e] * 128 + cp * 4);
        w[j] = *(const float4*)(&exs[wvx][e][0]);
      }
#pragma unroll
      for (int j = 0; j < 4; ++j) {
        f2v x01 = b2f2(r[j].x), x23 = b2f2(r[j].y);
        a01[0] += w[j].x * x01; a23[0] += w[j].x * x23;
        a01[1] += w[j].y * x01; a23[1] += w[j].y * x23;
        a01[2] += w[j].z * x01; a23[2] += w[j].z * x23;
        a01[3] += w[j].w * x01; a23[3] += w[j].w * x23;
      }
    }
    for (; i < cnt; i += 2) {
      uint2 r = *(const uint2*)(xb + (size_t)srcs[wvx][i] * 128 + cp * 4);
      float4 w = *(const float4*)(&exs[wvx][i][0]);
      f2v x01 = b2f2(r.x), x23 = b2f2(r.y);
      a01[0] += w.x * x01; a23[0] += w.x * x23;
      a01[1] += w.y * x01; a23[1] += w.y * x23;
      a01[2] += w.z * x01; a23[2] += w.z * x23;
      a01[3] += w.w * x01; a23[3] += w.w * x23;
    }
  }
#pragma unroll
  for (int h = 0; h < 4; ++h) {
    a01[h].x += __shfl_xor(a01[h].x, 32);
    a01[h].y += __shfl_xor(a01[h].y, 32);
    a23[h].x += __shfl_xor(a23[h].x, 32);
    a23[h].y += __shfl_xor(a23[h].y, 32);
  }
  if (slot == 0) {
    float inv[4] = {1.f / d0, 1.f / d1, 1.f / d2, 1.f / d3};
    size_t rb = (size_t)n * 512 + cp * 4;
#pragma unroll
    for (int h = 0; h < 4; ++h) {
      ushort4 o = {f2b(a01[h].x * inv[h]), f2b(a01[h].y * inv[h]),
                   f2b(a23[h].x * inv[h]), f2b(a23[h].y * inv[h])};
      *(ushort4*)(aggx + rb + h * 128) = o;
    }
  }
}

// ---------------- GAT layer-2 aggregation: 1 wave per node, H=1 ----------
__global__ __launch_bounds__(256) void gat_agg1_k(
    const int* __restrict__ offsets, const int2* __restrict__ csr,
    const unsigned short* __restrict__ h, const float* __restrict__ as_,
    const float* __restrict__ ad_, const float* __restrict__ bias,
    unsigned short* __restrict__ out) {
  __shared__ float exs[4][64];
  __shared__ int srcs[4][64];
  int wvx = threadIdx.x >> 6, lane = threadIdx.x & 63;
  int n = blockIdx.x * 4 + wvx;
  int slot = lane >> 4, cp = lane & 15;
  int beg = offsets[n], end = offsets[n + 1];
  float adn = ad_[n];
  float eself = __expf(lrelu(as_[n] + adn));
  float den = eself;
  f2v a01 = 0.f, a23 = 0.f;
  if (slot == 0) {
    uint2 sv = *(const uint2*)(h + (size_t)n * 64 + cp * 4);
    a01 = eself * b2f2(sv.x);
    a23 = eself * b2f2(sv.y);
  }
  for (int base = beg; base < end; base += 64) {
    int cnt = min(64, end - base);
    int src = 0;
    float ex = 0.f;
    if (lane < cnt) {
      src = csr[base + lane].x;
      ex = __expf(lrelu(as_[src] + adn));
    }
    float s = ex;
#pragma unroll
    for (int off = 32; off; off >>= 1) s += __shfl_xor(s, off);
    den += s;
    exs[wvx][lane] = ex;
    srcs[wvx][lane] = src;
    __builtin_amdgcn_wave_barrier();
    int i = slot;
    for (; i + 12 < cnt; i += 16) {
      uint2 r[4];
      int i0 = i, i1 = i + 4, i2 = i + 8, i3 = i + 12;
      r[0] = *(const uint2*)(h + (size_t)srcs[wvx][i0] * 64 + cp * 4);
      r[1] = *(const uint2*)(h + (size_t)srcs[wvx][i1] * 64 + cp * 4);
      r[2] = *(const uint2*)(h + (size_t)srcs[wvx][i2] * 64 + cp * 4);
      r[3] = *(const uint2*)(h + (size_t)srcs[wvx][i3] * 64 + cp * 4);
      float w0 = exs[wvx][i0], w1 = exs[wvx][i1], w2 = exs[wvx][i2], w3 = exs[wvx][i3];
      a01 += w0 * b2f2(r[0].x); a23 += w0 * b2f2(r[0].y);
      a01 += w1 * b2f2(r[1].x); a23 += w1 * b2f2(r[1].y);
      a01 += w2 * b2f2(r[2].x); a23 += w2 * b2f2(r[2].y);
      a01 += w3 * b2f2(r[3].x); a23 += w3 * b2f2(r[3].y);
    }
    for (; i < cnt; i += 4) {
      int si = srcs[wvx][i];
      float w = exs[wvx][i];
      uint2 r = *(const uint2*)(h + (size_t)si * 64 + cp * 4);
      a01 += w * b2f2(r.x);
      a23 += w * b2f2(r.y);
    }
  }
#pragma unroll
  for (int off = 16; off <= 32; off <<= 1) {
    a01.x += __shfl_xor(a01.x, off);
    a01.y += __shfl_xor(a01.y, off);
    a23.x += __shfl_xor(a23.x, off);
    a23.y += __shfl_xor(a23.y, off);
  }
  if (slot == 0) {
    float inv = 1.f / den;
    float4 b4 = *(const float4*)(bias + cp * 4);
    ushort4 ov;
    ov.x = f2b(a01.x * inv + b4.x);
    ov.y = f2b(a01.y * inv + b4.y);
    ov.z = f2b(a23.x * inv + b4.z);
    ov.w = f2b(a23.y * inv + b4.w);
    *(ushort4*)(out + (size_t)n * 64 + cp * 4) = ov;
  }
}

// ---------------- dst-grouped edge MLP: 1 wave per dst node ---------------
__global__ __launch_bounds__(256) void edge_out_k(
    const int* __restrict__ offsets, const int2* __restrict__ csr,
    const unsigned short* __restrict__ pq,
    const float* __restrict__ mb1, const float* __restrict__ w2,
    const float* __restrict__ mb2, float* __restrict__ out) {
  int wvx = threadIdx.x >> 6, lane = threadIdx.x & 63;
  int n = blockIdx.x * 4 + wvx;
  int slot = lane >> 4, cp = lane & 15;
  int beg = offsets[n], end = offsets[n + 1];
  uint2 qv = *(const uint2*)(pq + (size_t)n * 128 + 64 + cp * 4);
  f2v base01 = b2f2(qv.x), base23 = b2f2(qv.y);
  {
    float4 mb = *(const float4*)(mb1 + cp * 4);
    base01.x += mb.x; base01.y += mb.y;
    base23.x += mb.z; base23.y += mb.w;
  }
  f2v w01, w23;
  {
    float4 wv4 = *(const float4*)(w2 + cp * 4);
    w01.x = wv4.x; w01.y = wv4.y; w23.x = wv4.z; w23.y = wv4.w;
  }
  float b2v = mb2[0];
  for (int base = beg; base < end; base += 8) {
    int i0 = base + slot, i1 = base + 4 + slot;
    bool ok0 = (i0 < end), ok1 = (i1 < end);
    int2 se0 = {0, 0}, se1 = {0, 0};
    if (ok0) se0 = csr[i0];
    if (ok1) se1 = csr[i1];
    float r0 = 0.f, r1 = 0.f;
    if (ok0) {
      uint2 pv = *(const uint2*)(pq + (size_t)se0.x * 128 + cp * 4);
      f2v v01 = b2f2(pv.x) + base01;
      f2v v23 = b2f2(pv.y) + base23;
      v01.x = fmaxf(v01.x, 0.f); v01.y = fmaxf(v01.y, 0.f);
      v23.x = fmaxf(v23.x, 0.f); v23.y = fmaxf(v23.y, 0.f);
      f2v rv = v01 * w01 + v23 * w23;
      r0 = rv.x + rv.y;
    }
    if (ok1) {
      uint2 pv = *(const uint2*)(pq + (size_t)se1.x * 128 + cp * 4);
      f2v v01 = b2f2(pv.x) + base01;
      f2v v23 = b2f2(pv.y) + base23;
      v01.x = fmaxf(v01.x, 0.f); v01.y = fmaxf(v01.y, 0.f);
      v23.x = fmaxf(v23.x, 0.f); v23.y = fmaxf(v23.y, 0.f);
      f2v rv = v01 * w01 + v23 * w23;
      r1 = rv.x + rv.y;
    }
#pragma unroll
    for (int off = 8; off; off >>= 1) {
      r0 += __shfl_xor(r0, off);
      r1 += __shfl_xor(r1, off);
    }
    if (cp == 0) {
      if (ok0) out[se0.y] = r0 + b2v;
      if (ok1) out[se1.y] = r1 + b2v;
    }
  }
}

extern "C" void kernel_launch(void* const* d_in, const int* in_sizes, int n_in,
                              void* d_out, int out_size, void* d_ws, size_t ws_size,
                              hipStream_t stream) {
  const float* x = (const float*)d_in[0];
  const int* ei = (const int*)d_in[1];
  const float* W1 = (const float*)d_in[2];
  const float* as1w = (const float*)d_in[3];
  const float* ad1w = (const float*)d_in[4];
  const float* b1 = (const float*)d_in[5];
  const float* W2 = (const float*)d_in[6];
  const float* as2w = (const float*)d_in[7];
  const float* ad2w = (const float*)d_in[8];
  const float* b2 = (const float*)d_in[9];
  const float* mw1 = (const float*)d_in[10];
  const float* mb1 = (const float*)d_in[11];
  const float* mw2 = (const float*)d_in[12];
  const float* mb2 = (const float*)d_in[13];
  float* out = (float*)d_out;

  char* ws = (char*)d_ws;
  size_t o = 0;
  auto alloc = [&](size_t bytes) {
    void* ptr = ws + o;
    o += (bytes + 255) & ~(size_t)255;
    return ptr;
  };
  int* counts = (int*)alloc((size_t)NN * 4);
  int* offsets = (int*)alloc((size_t)(NN + 1) * 4);
  int* cursor = (int*)alloc((size_t)NN * 4);
  int* bsums = (int*)alloc((size_t)NB * 4);
  int2* csr = (int2*)alloc((size_t)NE * 8);
  unsigned short* xb = (unsigned short*)alloc((size_t)NN * 128 * 2);
  unsigned short* w1t = (unsigned short*)alloc((size_t)256 * 128 * 2);
  unsigned short* w2t = (unsigned short*)alloc((size_t)64 * 256 * 2);
  unsigned short* pqt = (unsigned short*)alloc((size_t)128 * 64 * 2);
  float* watt = (float*)alloc((size_t)8 * 128 * 4);
  unsigned short* big = (unsigned short*)alloc((size_t)NN * 512 * 2);  // aggx -> h2b/pq
  float* a_s1 = (float*)alloc((size_t)NN * 4 * 4);
  float* a_d1 = (float*)alloc((size_t)NN * 4 * 4);
  unsigned short* x2b = (unsigned short*)alloc((size_t)NN * 256 * 2);
  unsigned short* yb = (unsigned short*)alloc((size_t)NN * 64 * 2);
  unsigned short* aggx = big;                  // NN*512, dead after hx2
  unsigned short* h2b = big;                   // NN*64
  unsigned short* pq = big + (size_t)NN * 64;  // NN*128, [p|q]

  // CSR build + conversions + folded attention weights (all in prep_k)
  hipMemsetAsync(counts, 0, (size_t)NN * 4, stream);
  prep_k<<<NHB + (NX4 + NW1 + NW2 + NPQ + NWATT + 255) / 256, 256, 0, stream>>>(
      ei, counts, x, W1, W2, mw1, as1w, ad1w, xb, w1t, w2t, pqt, watt);
  attdot1_k<<<(NN + 31) / 32, 256, 0, stream>>>(x, watt, a_s1, a_d1);
  scan_bsum_k<<<NB, 256, 0, stream>>>(counts, bsums);
  scan_final_k<<<NB, 256, 0, stream>>>(counts, bsums, offsets, cursor);
  scatter_k<<<(NE + 255) / 256, 256, 0, stream>>>(ei, cursor, csr);

  int gy = (NN + 63) / 64;
  // Layer 1 (input-space aggregation): aggregate x-rows; post-GEMM per head
  gat_aggx_k<<<NN / 4, 256, 0, stream>>>(offsets, csr, xb, a_s1, a_d1, aggx);
  mgemm_hx2_k<<<dim3(4, gy), 256, 0, stream>>>(aggx, w1t, b1, x2b);

  // Layer 2: h2 = x2 @ W2 (MFMA) + fused dots; aggregate -> y (bf16)
  mgemm_k<1><<<dim3(1, gy), 256, 0, stream>>>(x2b, 256, w2t, 256, h2b, 64,
                                              NN, 64, 256, as2w, ad2w, a_s1, a_d1, 1);
  gat_agg1_k<<<NN / 4, 256, 0, stream>>>(offsets, csr, h2b, a_s1, a_d1, b2, yb);

  // Edge MLP: pq = y @ [mw1[:64] | mw1[64:]]  (one MFMA GEMM, N=128)
  mgemm_k<0><<<dim3(2, gy), 256, 0, stream>>>(yb, 64, pqt, 64, pq, 128,
                                              NN, 128, 64, nullptr, nullptr,
                                              nullptr, nullptr, 0);

  // Final per-edge output (dst-grouped)
  edge_out_k<<<NN / 4, 256, 0, stream>>>(offsets, csr, pq, mb1, mw2, mb2, out);
}